// Round 2
// baseline (873.891 us; speedup 1.0000x reference)
//
#include <hip/hip_runtime.h>

#define C 128
#define NPOS 16384      // 128*128 elements per (b,line) slab
#define PLANE 2097152   // 128*128*128 elements per batch

// ---------------------------------------------------------------------------
// Layouts (all fp32):
//   x,y,out : [B][C][H][W]
//   xt      : [B][W][H][C]  (phase-1 scan input, per-(b,w) slab of [H][C])
//   yt1     : [B][W][H][C]  (phase-1 gate)
//   yt2     : [B][H][W][C]  (phase-2 gate, per-(b,h) slab of [W][C])
//   hs_t/hn_t: [B][H][W][C] (phase-1 output == phase-2 input slabs)
//   outA    : [B][H][W][C] = hse+hsw   (reuses xt)
//   outB    : [B][H][W][C] = hne+hnw   (reuses yt1)
// ---------------------------------------------------------------------------

__global__ __launch_bounds__(256) void k_transpose_x(const float* __restrict__ x,
                                                     float* __restrict__ xt) {
  __shared__ float tile[128][129];
  const int b = blockIdx.x >> 7;
  const int h = blockIdx.x & 127;
  const int t = threadIdx.x;
  const int half = t >> 7;
  const int lane = t & 127;
  const float* src = x + (size_t)b * PLANE + (size_t)h * 128;  // [c][w]
  for (int c0 = 0; c0 < 128; c0 += 2) {
    const int c = c0 + half;
    tile[c][lane] = src[(size_t)c * NPOS + lane];
  }
  __syncthreads();
  float* dst = xt + (size_t)b * PLANE + (size_t)h * 128;  // [w][c] @ w*16384 + c
  for (int w0 = 0; w0 < 128; w0 += 2) {
    const int w = w0 + half;
    dst[(size_t)w * NPOS + lane] = tile[lane][w];
  }
}

__global__ __launch_bounds__(256) void k_transpose_y(const float* __restrict__ y,
                                                     float* __restrict__ yt1,
                                                     float* __restrict__ yt2) {
  __shared__ float tile[128][129];
  const int b = blockIdx.x >> 7;
  const int h = blockIdx.x & 127;
  const int t = threadIdx.x;
  const int half = t >> 7;
  const int lane = t & 127;
  const float* src = y + (size_t)b * PLANE + (size_t)h * 128;
  for (int c0 = 0; c0 < 128; c0 += 2) {
    const int c = c0 + half;
    tile[c][lane] = src[(size_t)c * NPOS + lane];
  }
  __syncthreads();
  float* d1 = yt1 + (size_t)b * PLANE + (size_t)h * 128;   // [w][c] @ w*16384 + c
  float* d2 = yt2 + ((size_t)(b * 128 + h)) * NPOS;        // [w][c] @ w*128 + c
  for (int w0 = 0; w0 < 128; w0 += 2) {
    const int w = w0 + half;
    const float v = tile[lane][w];
    d1[(size_t)w * NPOS + lane] = v;
    d2[(size_t)w * 128 + lane] = v;
  }
}

__device__ __forceinline__ float4 f4fma(float4 a, float4 b, float4 acc) {
  acc.x = fmaf(a.x, b.x, acc.x);
  acc.y = fmaf(a.y, b.y, acc.y);
  acc.z = fmaf(a.z, b.z, acc.z);
  acc.w = fmaf(a.w, b.w, acc.w);
  return acc;
}

// ---------------------------------------------------------------------------
// One directional gated scan for a single line, fused FF + recurrent conv.
// 256 threads. Thread (wave wv, lane l): q = l>>4 (ci quarter), cs = l&15,
// owns channel pair ch = wv*32 + cs*2 and ci range [q*32, q*32+32).
// Per step: both 32-long partial dots in regs (Wa,Wb resident, 128 VGPRs),
// in-wave reduce over quarters via shfl_xor(16/32), ONE barrier per step.
// h double-buffered in padded LDS (chunk stride 36 floats -> conflict-free).
// ACCUM: read-modify-write add into out (used by the 2nd scan of each pair).
// ---------------------------------------------------------------------------
template <bool RELU_FIRST, bool REVERSE, bool ACCUM>
__device__ __forceinline__ void scan_line(
    const float* __restrict__ in_slab, const float* __restrict__ gate_slab,
    float* __restrict__ out_base, int out_stride,
    const float* __restrict__ Wa, const float* __restrict__ Ba,
    const float* __restrict__ Wb, const float* __restrict__ Bb,
    float* __restrict__ hbuf /* [2][144] */) {
  const int t = threadIdx.x;
  const int wv = t >> 6;
  const int l = t & 63;
  const int q = l >> 4;
  const int cs = l & 15;
  const int ch = wv * 32 + cs * 2;
  const bool leader = (q == 0);

  // Weight fragments: rows ch, ch+1, ci in [q*32, q*32+32). 128 floats total.
  float4 wa[2][8], wb[2][8];
  {
    const float* wa0 = Wa + (size_t)ch * C + q * 32;
    const float* wb0 = Wb + (size_t)ch * C + q * 32;
#pragma unroll
    for (int i = 0; i < 8; ++i) {
      wa[0][i] = ((const float4*)wa0)[i];
      wa[1][i] = ((const float4*)(wa0 + C))[i];
      wb[0][i] = ((const float4*)wb0)[i];
      wb[1][i] = ((const float4*)(wb0 + C))[i];
    }
  }
  float ba0 = 0.f, ba1 = 0.f, bb0 = 0.f, bb1 = 0.f;
  float g0 = 0.f, g1 = 0.f, old0 = 0.f, old1 = 0.f;
  if (leader) {
    ba0 = Ba[ch];
    ba1 = Ba[ch + 1];
    bb0 = Bb[ch];
    bb1 = Bb[ch + 1];
  }

  auto P = [](int s) -> int { return REVERSE ? (127 - s) : s; };

  // ---- step 0: h0 = (relu?)(in[0]) ----
  if (leader) {
    float2 h2 = *(const float2*)(in_slab + (size_t)P(0) * C + ch);
    if (RELU_FIRST) {
      h2.x = fmaxf(h2.x, 0.f);
      h2.y = fmaxf(h2.y, 0.f);
    }
    float ox = h2.x, oy = h2.y;
    if (ACCUM) {
      const float2 o = *(const float2*)(out_base + (size_t)P(0) * out_stride + ch);
      ox += o.x;
      oy += o.y;
    }
    *(float2*)(out_base + (size_t)P(0) * out_stride + ch) = make_float2(ox, oy);
    hbuf[wv * 36 + cs * 2] = h2.x;
    hbuf[wv * 36 + cs * 2 + 1] = h2.y;
    const float2 g = *(const float2*)(gate_slab + (size_t)P(0) * C + ch);  // gate for step 1
    g0 = g.x;
    g1 = g.y;
    if (ACCUM) {
      const float2 o = *(const float2*)(out_base + (size_t)P(1) * out_stride + ch);
      old0 = o.x;
      old1 = o.y;
    }
  }

  // ---- prologue: ra for step 1 from x[P(1)] ----
  float4 xq[8];
  {
    const float* xp = in_slab + (size_t)P(1) * C + q * 32;
#pragma unroll
    for (int i = 0; i < 8; ++i) xq[i] = ((const float4*)xp)[i];
  }
  float ra0, ra1;
  {
    float4 c0 = {0, 0, 0, 0}, c1 = {0, 0, 0, 0};
#pragma unroll
    for (int i = 0; i < 8; ++i) {
      c0 = f4fma(wa[0][i], xq[i], c0);
      c1 = f4fma(wa[1][i], xq[i], c1);
    }
    ra0 = (c0.x + c0.y) + (c0.z + c0.w);
    ra1 = (c1.x + c1.y) + (c1.z + c1.w);
    ra0 += __shfl_xor(ra0, 16);
    ra0 += __shfl_xor(ra0, 32);
    ra1 += __shfl_xor(ra1, 16);
    ra1 += __shfl_xor(ra1, 32);
  }
  // prefetch x[P(2)]
  {
    const float* xp = in_slab + (size_t)P(2) * C + q * 32;
#pragma unroll
    for (int i = 0; i < 8; ++i) xq[i] = ((const float4*)xp)[i];
  }
  __syncthreads();

#pragma unroll 1
  for (int s = 1; s < 128; ++s) {
    // recurrent dot on h_{s-1}
    const float* hq = hbuf + ((s - 1) & 1) * 144 + q * 36;
    float4 b0 = {0, 0, 0, 0}, b1 = {0, 0, 0, 0};
#pragma unroll
    for (int i = 0; i < 8; ++i) {
      const float4 hv = ((const float4*)hq)[i];
      b0 = f4fma(wb[0][i], hv, b0);
      b1 = f4fma(wb[1][i], hv, b1);
    }
    float rb0 = (b0.x + b0.y) + (b0.z + b0.w);
    float rb1 = (b1.x + b1.y) + (b1.z + b1.w);

    // feedforward dot for step s+1 from xq (= x[P(s+1)], loaded last step)
    float4 c0 = {0, 0, 0, 0}, c1 = {0, 0, 0, 0};
#pragma unroll
    for (int i = 0; i < 8; ++i) {
      c0 = f4fma(wa[0][i], xq[i], c0);
      c1 = f4fma(wa[1][i], xq[i], c1);
    }
    float rn0 = (c0.x + c0.y) + (c0.z + c0.w);
    float rn1 = (c1.x + c1.y) + (c1.z + c1.w);

    // reload xq <- x[P(s+2)] (clamped; redundant at the tail, harmless)
    {
      const int sn = (s + 2 <= 127) ? (s + 2) : 127;
      const float* xp = in_slab + (size_t)P(sn) * C + q * 32;
#pragma unroll
      for (int i = 0; i < 8; ++i) xq[i] = ((const float4*)xp)[i];
    }

    // in-wave reductions over the 4 ci-quarters
    rb0 += __shfl_xor(rb0, 16);
    rb0 += __shfl_xor(rb0, 32);
    rb1 += __shfl_xor(rb1, 16);
    rb1 += __shfl_xor(rb1, 32);
    rn0 += __shfl_xor(rn0, 16);
    rn0 += __shfl_xor(rn0, 32);
    rn1 += __shfl_xor(rn1, 16);
    rn1 += __shfl_xor(rn1, 32);

    if (leader) {
      // prefetch gate for step s+1 and old-out for RMW at s+1
      const float2 g = *(const float2*)(gate_slab + (size_t)P(s) * C + ch);
      float on0 = 0.f, on1 = 0.f;
      if (ACCUM && s < 127) {
        const float2 o = *(const float2*)(out_base + (size_t)P(s + 1) * out_stride + ch);
        on0 = o.x;
        on1 = o.y;
      }
      const float hx = fmaxf(ra0 + ba0 + (rb0 + bb0) * g0, 0.f);
      const float hy = fmaxf(ra1 + ba1 + (rb1 + bb1) * g1, 0.f);
      hbuf[(s & 1) * 144 + wv * 36 + cs * 2] = hx;
      hbuf[(s & 1) * 144 + wv * 36 + cs * 2 + 1] = hy;
      float ox = hx, oy = hy;
      if (ACCUM) {
        ox += old0;
        oy += old1;
      }
      *(float2*)(out_base + (size_t)P(s) * out_stride + ch) = make_float2(ox, oy);
      g0 = g.x;
      g1 = g.y;
      old0 = on0;
      old1 = on1;
    }
    ra0 = rn0;
    ra1 = rn1;
    __syncthreads();
  }
}

// Phase 1: south (hs) + north (hn) scans over H. 1024 blocks: [scan(2)][b(4)][w(128)]
__global__ __launch_bounds__(256, 2) void k_scan_ph1(
    const float* __restrict__ xt, const float* __restrict__ yt1,
    float* __restrict__ hs_t, float* __restrict__ hn_t,
    const float* w1, const float* b1, const float* w2, const float* b2,
    const float* w9, const float* b9, const float* w10, const float* b10) {
  __shared__ __align__(16) float hbuf[288];
  const int id = blockIdx.x;
  const int scan = id >> 9;
  const int col = id & 511;  // b*128 + w
  const int b = col >> 7, wc = col & 127;
  const float* in = xt + (size_t)col * NPOS;
  const float* gt = yt1 + (size_t)col * NPOS;
  if (scan == 0)
    scan_line<false, false, false>(in, gt, hs_t + (size_t)b * PLANE + (size_t)wc * C, NPOS,
                                   w1, b1, w2, b2, hbuf);
  else
    scan_line<true, true, false>(in, gt, hn_t + (size_t)b * PLANE + (size_t)wc * C, NPOS,
                                 w9, b9, w10, b10, hbuf);
}

// Phase 2a: SE (hs->outA) and NE (hn->outB), forward, store.
__global__ __launch_bounds__(256, 2) void k_scan_ph2a(
    const float* __restrict__ hs_t, const float* __restrict__ hn_t,
    const float* __restrict__ yt2, float* __restrict__ outA, float* __restrict__ outB,
    const float* w4, const float* b4, const float* w5, const float* b5,
    const float* w12, const float* b12, const float* w13, const float* b13) {
  __shared__ __align__(16) float hbuf[288];
  const int id = blockIdx.x;
  const int grp = id >> 9;
  const int col = id & 511;  // b*128 + h
  const size_t base = (size_t)col * NPOS;
  const float* gt = yt2 + base;
  if (grp == 0)
    scan_line<true, false, false>(hs_t + base, gt, outA + base, C, w4, b4, w5, b5, hbuf);
  else
    scan_line<true, false, false>(hn_t + base, gt, outB + base, C, w12, b12, w13, b13, hbuf);
}

// Phase 2b: SW (hs, RMW-add into outA) and NW (hn, RMW-add into outB), reverse.
__global__ __launch_bounds__(256, 2) void k_scan_ph2b(
    const float* __restrict__ hs_t, const float* __restrict__ hn_t,
    const float* __restrict__ yt2, float* __restrict__ outA, float* __restrict__ outB,
    const float* w7, const float* b7, const float* w8, const float* b8,
    const float* w15, const float* b15, const float* w16, const float* b16) {
  __shared__ __align__(16) float hbuf[288];
  const int id = blockIdx.x;
  const int grp = id >> 9;
  const int col = id & 511;  // b*128 + h
  const size_t base = (size_t)col * NPOS;
  const float* gt = yt2 + base;
  if (grp == 0)
    scan_line<true, true, true>(hs_t + base, gt, outA + base, C, w7, b7, w8, b8, hbuf);
  else
    scan_line<true, true, true>(hn_t + base, gt, outB + base, C, w15, b15, w16, b16, hbuf);
}

// out[b][c][h][w] = outA[b][h][w][c] + outB[b][h][w][c]
__global__ __launch_bounds__(256) void k_final(const float* __restrict__ outA,
                                               const float* __restrict__ outB,
                                               float* __restrict__ out) {
  __shared__ float tile[128][129];
  const int b = blockIdx.x >> 7;
  const int h = blockIdx.x & 127;
  const int t = threadIdx.x;
  const int half = t >> 7;
  const int lane = t & 127;
  const float* pa = outA + ((size_t)(b * 128 + h)) * NPOS;  // [w][c]
  const float* pb = outB + ((size_t)(b * 128 + h)) * NPOS;
  for (int w0 = 0; w0 < 128; w0 += 2) {
    const int w = w0 + half;
    tile[w][lane] = pa[(size_t)w * 128 + lane] + pb[(size_t)w * 128 + lane];
  }
  __syncthreads();
  float* dst = out + (size_t)b * PLANE + (size_t)h * 128;  // [c][w]
  for (int c0 = 0; c0 < 128; c0 += 2) {
    const int c = c0 + half;
    dst[(size_t)c * NPOS + lane] = tile[lane][c];
  }
}

extern "C" void kernel_launch(void* const* d_in, const int* in_sizes, int n_in,
                              void* d_out, int out_size, void* d_ws, size_t ws_size,
                              hipStream_t stream) {
  const float* x = (const float*)d_in[0];
  const float* y = (const float*)d_in[1];
  const float* w1 = (const float*)d_in[2];
  const float* b1 = (const float*)d_in[3];
  const float* w2 = (const float*)d_in[4];
  const float* b2 = (const float*)d_in[5];
  const float* w4 = (const float*)d_in[6];
  const float* b4 = (const float*)d_in[7];
  const float* w5 = (const float*)d_in[8];
  const float* b5 = (const float*)d_in[9];
  const float* w7 = (const float*)d_in[10];
  const float* b7 = (const float*)d_in[11];
  const float* w8 = (const float*)d_in[12];
  const float* b8 = (const float*)d_in[13];
  const float* w9 = (const float*)d_in[14];
  const float* b9 = (const float*)d_in[15];
  const float* w10 = (const float*)d_in[16];
  const float* b10 = (const float*)d_in[17];
  const float* w12 = (const float*)d_in[18];
  const float* b12 = (const float*)d_in[19];
  const float* w13 = (const float*)d_in[20];
  const float* b13 = (const float*)d_in[21];
  const float* w15 = (const float*)d_in[22];
  const float* b15 = (const float*)d_in[23];
  const float* w16 = (const float*)d_in[24];
  const float* b16 = (const float*)d_in[25];

  const size_t N1 = (size_t)4 * C * 128 * 128;  // 8M floats = 32MB
  if (ws_size < 5 * N1 * sizeof(float)) return;

  float* ws = (float*)d_ws;
  float* xt = ws;
  float* yt1 = ws + N1;
  float* yt2 = ws + 2 * N1;
  float* hs_t = ws + 3 * N1;
  float* hn_t = ws + 4 * N1;
  float* outA = xt;   // free after phase 1
  float* outB = yt1;  // free after phase 1

  dim3 blk(256);
  k_transpose_x<<<512, blk, 0, stream>>>(x, xt);
  k_transpose_y<<<512, blk, 0, stream>>>(y, yt1, yt2);
  k_scan_ph1<<<1024, blk, 0, stream>>>(xt, yt1, hs_t, hn_t, w1, b1, w2, b2, w9, b9, w10, b10);
  k_scan_ph2a<<<1024, blk, 0, stream>>>(hs_t, hn_t, yt2, outA, outB,
                                        w4, b4, w5, b5, w12, b12, w13, b13);
  k_scan_ph2b<<<1024, blk, 0, stream>>>(hs_t, hn_t, yt2, outA, outB,
                                        w7, b7, w8, b8, w15, b15, w16, b16);
  k_final<<<512, blk, 0, stream>>>(outA, outB, (float*)d_out);
}